// Round 10
// baseline (66.530 us; speedup 1.0000x reference)
//
#include <hip/hip_runtime.h>
#include <hip/hip_bf16.h>

typedef __attribute__((ext_vector_type(4)))  float f32x4;
typedef __attribute__((ext_vector_type(16))) float f32x16;
typedef __attribute__((ext_vector_type(8)))  short s16x8;
typedef unsigned short u16;
typedef unsigned int u32;

#define ALPHA 1.6986436f          /* sqrt(2*log2(e)) : dot(a*h, a*h) = sim*log2e */
#define LN2F  0.69314718056f
#define COFF  128.0f              /* static log2-domain offset for softmax */

__device__ __forceinline__ u16 f2bf(float x) {
  union { float f; u32 u; } v; v.f = x;
  u32 r = v.u + 0x7fffu + ((v.u >> 16) & 1u);
  return (u16)(r >> 16);
}

#if __has_builtin(__builtin_amdgcn_exp2f)
__device__ __forceinline__ float fexp2(float x) { return __builtin_amdgcn_exp2f(x); }
#else
__device__ __forceinline__ float fexp2(float x) { return exp2f(x); }
#endif
#if __has_builtin(__builtin_amdgcn_logf)
__device__ __forceinline__ float flog2(float x) { return __builtin_amdgcn_logf(x); }
#else
__device__ __forceinline__ float flog2(float x) { return log2f(x); }
#endif

// 8x fp32 -> packed bf16 (RNE) in 4 instructions
__device__ __forceinline__ s16x8 cvt8(float4 a, float4 b) {
  union { u32 w[4]; s16x8 v; } u;
  asm("v_cvt_pk_bf16_f32 %0, %1, %2" : "=v"(u.w[0]) : "v"(a.x), "v"(a.y));
  asm("v_cvt_pk_bf16_f32 %0, %1, %2" : "=v"(u.w[1]) : "v"(a.z), "v"(a.w));
  asm("v_cvt_pk_bf16_f32 %0, %1, %2" : "=v"(u.w[2]) : "v"(b.x), "v"(b.y));
  asm("v_cvt_pk_bf16_f32 %0, %1, %2" : "=v"(u.w[3]) : "v"(b.z), "v"(b.w));
  return u.v;
}

__device__ __forceinline__ f32x16 mfma32(s16x8 a, s16x8 b, f32x16 c) {
  return __builtin_amdgcn_mfma_f32_32x32x16_bf16(a, b, c, 0, 0, 0);
}
__device__ __forceinline__ f32x16 zero16() {
  f32x16 z;
#pragma unroll
  for (int i = 0; i < 16; ++i) z[i] = 0.f;
  return z;
}
__device__ __forceinline__ void gl16(const void* g, void* l) {
  __builtin_amdgcn_global_load_lds(
      (const __attribute__((address_space(1))) u32*)g,
      (__attribute__((address_space(3))) u32*)l, 16, 0, 0);
}

// =================== prep (fused): hbf + pos4 | axG + nall | nsub ============
// hbf row r: byte off = r*256 + ((2k) ^ ((r&7)<<4)), bf16 scaled by ALPHA.
// axG[kc][d][32B]: bf16(all_x[kc*16+kk][d]) at byte kc*4096 + d*32 + kk*2.
__global__ __launch_bounds__(256)
void prep_all(const float* __restrict__ h_i, const float* __restrict__ h_j,
              const float* __restrict__ all_x, const float* __restrict__ subx,
              u16* __restrict__ hbf, u16* __restrict__ axG,
              float* __restrict__ nall, float* __restrict__ nsub,
              float* __restrict__ pos4) {
  __shared__ float tile[64 * 132];
  int bid = blockIdx.x, tid = threadIdx.x;
  if (bid < 512) {
    // ---- hbf + pos4 ----
    int t = bid * 256 + tid;
    int row = t >> 4, kb = t & 15;
    const float* src = (row < 4096 ? h_i + (size_t)row * 128
                                   : h_j + (size_t)(row - 4096) * 128) + kb * 8;
    float4 f0 = *(const float4*)(src);
    float4 f1 = *(const float4*)(src + 4);
    float4 sa = {ALPHA * f0.x, ALPHA * f0.y, ALPHA * f0.z, ALPHA * f0.w};
    float4 sb = {ALPHA * f1.x, ALPHA * f1.y, ALPHA * f1.z, ALPHA * f1.w};
    s16x8 o = cvt8(sa, sb);
    char* dst = (char*)hbf + (size_t)row * 256 + ((kb * 16) ^ ((row & 7) << 4));
    *(s16x8*)dst = o;
    if (row < 4096) {   // fp32-exact positives
      const float* srcj = h_j + (size_t)row * 128 + kb * 8;
      float4 g0 = *(const float4*)(srcj);
      float4 g1 = *(const float4*)(srcj + 4);
      float dp = f0.x * g0.x + f0.y * g0.y + f0.z * g0.z + f0.w * g0.w
               + f1.x * g1.x + f1.y * g1.y + f1.z * g1.z + f1.w * g1.w;
      dp += __shfl_xor(dp, 1, 64);
      dp += __shfl_xor(dp, 2, 64);
      dp += __shfl_xor(dp, 4, 64);
      dp += __shfl_xor(dp, 8, 64);
      if ((tid & 15) == 0) pos4[row] = 2.0f * dp;
    }
  } else if (bid < 640) {
    // ---- axG + nall (64 k rows of all_x per block) ----
    int ab = bid - 512;           // 0..127
    int k0 = ab * 64;
#pragma unroll
    for (int j = 0; j < 8; ++j) {
      int idx = (j * 256 + tid) * 4;
      int kk = idx >> 7, d = idx & 127;
      *(float4*)&tile[kk * 132 + d] = *(const float4*)&all_x[(size_t)(k0 + kk) * 128 + d];
    }
    __syncthreads();
    {
      int kk = tid >> 2, q = tid & 3;
      float s = 0.f;
#pragma unroll
      for (int dd = 0; dd < 32; ++dd) { float v = tile[kk * 132 + q * 32 + dd]; s += v * v; }
      s += __shfl_xor(s, 1, 64);
      s += __shfl_xor(s, 2, 64);
      if (q == 0) nall[k0 + kk] = s;
    }
#pragma unroll
    for (int half = 0; half < 2; ++half) {
      int tgt = half * 256 + tid;
      int f = tgt >> 7, d = tgt & 127;    // kc-local f in 0..3
      int kc = ab * 4 + f;
      u16* dp = axG + (size_t)kc * 2048 + d * 16;
      s16x8 o0, o1;
#pragma unroll
      for (int kk = 0; kk < 8; ++kk) {
        o0[kk] = (short)f2bf(tile[(f * 16 + kk) * 132 + d]);
        o1[kk] = (short)f2bf(tile[(f * 16 + 8 + kk) * 132 + d]);
      }
      ((s16x8*)dp)[0] = o0; ((s16x8*)dp)[1] = o1;
    }
  } else {
    // ---- nsub ----
    int i = (bid - 640) * 256 + tid;
    const float* p = subx + (size_t)i * 128;
    float s = 0.f;
#pragma unroll
    for (int c = 0; c < 32; ++c) {
      float4 v = ((const float4*)p)[c];
      s += v.x * v.x + v.y * v.y + v.z * v.z + v.w * v.w;
    }
    nsub[i] = s;
  }
}

// =================== main (fused): graph (wave-autonomous) | contrast ========
// bid%3==0 -> graph (512 blocks x 4 independent wave-tasks = 2048):
//   task = (bid/3)*4 + w; mt = task>>4 (32 rows), kq = task&15 (512 k, 8x64).
//   Wave-private 2x4KB LDS tile, NO barriers: coalesced G loads -> cvt ->
//   swizzled ds_write -> same-wave lgkmcnt -> ds_read B-frags -> 16 MFMA.
//   t1/t2 folded as exact fp32 scalars during commit.
// bid%3 in {1,2} -> contrast (1024 blocks): cid=(bid/3)*2+(bid%3-1);
//   rt = cid>>5 (256 rows), oct = cid&31 (256 cols, 8 steps of 32).
__global__ __launch_bounds__(256, 2)
void main_fused(const float* __restrict__ G, const float* __restrict__ subx,
                const u16* __restrict__ axG, const float* __restrict__ nall,
                const float* __restrict__ nsub, const u16* __restrict__ hbf,
                float* __restrict__ spart, float* __restrict__ gpart) {
  __shared__ char pool[32768];
  int bid = blockIdx.x, tid = threadIdx.x;
  int lane = tid & 63, w = tid >> 6, il = lane & 31, hi = lane >> 5;
  int base = bid / 3, q = bid - base * 3;

  if (q == 0) {
    // ------------------ graph: one autonomous wave-task per wave ------------
    int task = base * 4 + w;
    int mt = task >> 4, kq = task & 15;
    int i0 = mt * 32;
    int kt0 = kq * 512;
    int sr = lane >> 4, sc = lane & 15;           // staging: row base, k-chunk
    const float* gws = G + (size_t)(i0 + sr) * 8192 + kt0 + sc * 4;
    const float* nws = nall + kt0 + sc * 4;
    char* buf0 = pool + w * 8192;
    char* buf1 = buf0 + 4096;
    const char* aBase = (const char*)axG + (size_t)(kq * 32) * 4096
                      + il * 32 + hi * 16;

    float nsb[8];
#pragma unroll
    for (int j = 0; j < 8; ++j) nsb[j] = nsub[i0 + sr + j * 4];

    f32x16 acc[4];
#pragma unroll
    for (int t = 0; t < 4; ++t) acc[t] = zero16();
    float p1 = 0.f, p2 = 0.f;
    float4 gr1[8], gr2[8];
    float4 na1, na2;

    auto gi = [&](int s, float4* gr, float4& na) {
#pragma unroll
      for (int j = 0; j < 8; ++j)
        gr[j] = *(const float4*)(gws + (size_t)j * 32768 + s * 64);
      na = *(const float4*)(nws + s * 64);
    };
    auto gc = [&](const float4* gr, const float4& na, char* buf) {
#pragma unroll
      for (int j = 0; j < 8; ++j) {
        float4 g = gr[j];
        u32 c0, c1;
        asm("v_cvt_pk_bf16_f32 %0, %1, %2" : "=v"(c0) : "v"(g.x), "v"(g.y));
        asm("v_cvt_pk_bf16_f32 %0, %1, %2" : "=v"(c1) : "v"(g.z), "v"(g.w));
        int r = sr + j * 4;
        *(uint2*)(buf + r * 128 + ((sc * 8) ^ ((r & 7) << 4))) = make_uint2(c0, c1);
        p1 += (g.x + g.y + g.z + g.w) * nsb[j];
        p2 += g.x * na.x + g.y * na.y + g.z * na.z + g.w * na.w;
      }
    };

    // prologue: tile0 staged; tiles 1,2 in flight
    gi(0, gr1, na1);
    gc(gr1, na1, buf0);
    gi(1, gr1, na1);
    gi(2, gr2, na2);
    asm volatile("s_waitcnt lgkmcnt(0)" ::: "memory");
    __builtin_amdgcn_sched_barrier(0);

#pragma unroll
    for (int s = 0; s < 8; ++s) {
      char* rb = (s & 1) ? buf1 : buf0;
      char* wb = (s & 1) ? buf0 : buf1;
      int swz = (il & 7) << 4;
      s16x8 B0 = *(const s16x8*)(rb + il * 128 + ((0  + hi * 16) ^ swz));
      s16x8 B1 = *(const s16x8*)(rb + il * 128 + ((32 + hi * 16) ^ swz));
      s16x8 B2 = *(const s16x8*)(rb + il * 128 + ((64 + hi * 16) ^ swz));
      s16x8 B3 = *(const s16x8*)(rb + il * 128 + ((96 + hi * 16) ^ swz));
#pragma unroll
      for (int kc4 = 0; kc4 < 4; ++kc4) {
        const char* ab = aBase + (size_t)(s * 4 + kc4) * 4096;
        s16x8 A0 = *(const s16x8*)(ab);
        s16x8 A1 = *(const s16x8*)(ab + 1024);
        s16x8 A2 = *(const s16x8*)(ab + 2048);
        s16x8 A3 = *(const s16x8*)(ab + 3072);
        s16x8 Bk = (kc4 == 0) ? B0 : (kc4 == 1) ? B1 : (kc4 == 2) ? B2 : B3;
        acc[0] = mfma32(A0, Bk, acc[0]);
        acc[1] = mfma32(A1, Bk, acc[1]);
        acc[2] = mfma32(A2, Bk, acc[2]);
        acc[3] = mfma32(A3, Bk, acc[3]);
      }
      if (s < 7) { if (s & 1) gc(gr2, na2, wb); else gc(gr1, na1, wb); }
      if (s < 5) { if (s & 1) gi(s + 3, gr2, na2); else gi(s + 3, gr1, na1); }
      asm volatile("s_waitcnt lgkmcnt(0)" ::: "memory");
      __builtin_amdgcn_sched_barrier(0);
    }

    // epilogue: acc[t][r] = y[d = t*32+(r&3)+8*(r>>2)+4*hi][i = i0+il]
    float p = p1 + p2;
#pragma unroll
    for (int t = 0; t < 4; ++t) {
      const float* sxr = subx + (size_t)(i0 + il) * 128 + t * 32 + hi * 4;
#pragma unroll
      for (int rq = 0; rq < 4; ++rq) {
        float4 sx = *(const float4*)(sxr + rq * 8);
        p -= 2.0f * (acc[t][rq * 4 + 0] * sx.x + acc[t][rq * 4 + 1] * sx.y +
                     acc[t][rq * 4 + 2] * sx.z + acc[t][rq * 4 + 3] * sx.w);
      }
    }
#pragma unroll
    for (int d = 1; d < 64; d <<= 1) p += __shfl_xor(p, d, 64);
    if (lane == 0) gpart[task] = p;
  } else {
    // ------------------ contrast ------------------
    int cid = base * 2 + (q - 1);
    int rt = cid >> 5, oct = cid & 31;
    int C0 = oct * 256;
    int rowbase = rt * 256 + w * 64;
    char (*clds)[8192] = (char(*)[8192])pool;
    s16x8 bf0[8], bf1[8];
#pragma unroll
    for (int rs = 0; rs < 2; ++rs) {
      int r = rowbase + rs * 32 + il;
      const char* rp = (const char*)hbf + (size_t)r * 256;
      int sw = (r & 7) << 4;
#pragma unroll
      for (int ks = 0; ks < 8; ++ks) {
        s16x8 v = *(const s16x8*)(rp + ((ks * 32 + hi * 16) ^ sw));
        if (rs == 0) bf0[ks] = v; else bf1[ks] = v;
      }
    }
    float s0 = 0.f, s1 = 0.f;
    auto stage = [&](int buf, int t) {
      const char* src = (const char*)hbf + (size_t)(C0 + t * 32) * 256 + tid * 16;
      char* dst = &clds[buf][0] + tid * 16;
      gl16(src, dst);
      gl16(src + 4096, dst + 4096);
    };
    stage(0, 0);
    __syncthreads();
    int cur = 0;
    for (int t = 0; t < 8; ++t) {
      if (t < 7) stage(cur ^ 1, t + 1);
      const char* basep = &clds[cur][0];
      s16x8 af[8];
#pragma unroll
      for (int ks = 0; ks < 8; ++ks)
        af[ks] = *(const s16x8*)(basep + il * 256 + ((ks * 32 + hi * 16) ^ ((il & 7) << 4)));
      f32x16 A0 = zero16(), A1 = zero16();
#pragma unroll
      for (int ks = 0; ks < 8; ++ks) {
        A0 = mfma32(af[ks], bf0[ks], A0);
        A1 = mfma32(af[ks], bf1[ks], A1);
      }
      int cb = C0 + t * 32;
      bool d0 = (cb == rowbase), d1 = (cb == rowbase + 32);
      if (!(d0 | d1)) {      // wave-uniform fast path: no diagonal in this tile
#pragma unroll
        for (int r = 0; r < 16; ++r) {
          s0 += fexp2(A0[r] - COFF);
          s1 += fexp2(A1[r] - COFF);
        }
      } else {
#pragma unroll
        for (int r = 0; r < 16; ++r) {
          int jc = (r & 3) + 8 * (r >> 2) + 4 * hi;
          float t0 = fexp2(A0[r] - COFF);
          float t1 = fexp2(A1[r] - COFF);
          if (d0 && jc == il) t0 = 0.f;
          if (d1 && jc == il) t1 = 0.f;
          s0 += t0; s1 += t1;
        }
      }
      __syncthreads();
      cur ^= 1;
    }
    s0 += __shfl_xor(s0, 32, 64);
    s1 += __shfl_xor(s1, 32, 64);
    if (hi == 0) {
      spart[oct * 8192 + rowbase + il]      = s0;
      spart[oct * 8192 + rowbase + 32 + il] = s1;
    }
  }
}

// =================== epilogue stage 1: per-row lse, 32-block parallel ========
__global__ __launch_bounds__(256)
void epilogue1(const float* __restrict__ spart, const float* __restrict__ pos4,
               float* __restrict__ cpart) {
  int tid = threadIdx.x;
  int row = blockIdx.x * 256 + tid;
  float S = 0.f;
#pragma unroll
  for (int o = 0; o < 32; ++o) S += spart[o * 8192 + row];
  float c = LN2F * (COFF + flog2(S)) - pos4[row & 4095];
#pragma unroll
  for (int d = 1; d < 64; d <<= 1) c += __shfl_xor(c, d, 64);
  __shared__ float ws4[4];
  int l = tid & 63, w = tid >> 6;
  if (l == 0) ws4[w] = c;
  __syncthreads();
  if (tid == 0) cpart[blockIdx.x] = ws4[0] + ws4[1] + ws4[2] + ws4[3];
}

// =================== final deterministic scalar reduction ====================
__global__ __launch_bounds__(256)
void final_sum(const float* __restrict__ cpart, const float* __restrict__ gpart,
               float* __restrict__ out) {
  int tid = threadIdx.x;
  double gd = 0.0;
  for (int idx = tid; idx < 2048; idx += 256) gd += (double)gpart[idx];
  double cd = (tid < 32) ? (double)cpart[tid] : 0.0;
#pragma unroll
  for (int d = 1; d < 64; d <<= 1) {
    cd += __shfl_xor(cd, d, 64);
    gd += __shfl_xor(gd, d, 64);
  }
  __shared__ double wc[4], wg[4];
  int l = tid & 63, w = tid >> 6;
  if (l == 0) { wc[w] = cd; wg[w] = gd; }
  __syncthreads();
  if (tid == 0) {
    double C = wc[0] + wc[1] + wc[2] + wc[3];
    double Gs = wg[0] + wg[1] + wg[2] + wg[3];
    out[0] = (float)(C / 8192.0 + Gs / (4096.0 * 8192.0));
  }
}

extern "C" void kernel_launch(void* const* d_in, const int* in_sizes, int n_in,
                              void* d_out, int out_size, void* d_ws, size_t ws_size,
                              hipStream_t stream) {
  const float* h_i = (const float*)d_in[0];
  const float* h_j = (const float*)d_in[1];
  const float* G   = (const float*)d_in[2];
  const float* sx  = (const float*)d_in[3];
  const float* ax  = (const float*)d_in[4];
  char* ws = (char*)d_ws;
  u16*   hbf   = (u16*)(ws);                    // 2,097,152 B
  u16*   axG   = (u16*)(ws + 2097152);          // 2,097,152 B (512 kc x 4KB)
  float* nall  = (float*)(ws + 4194304);        //    32,768 B
  float* nsub  = (float*)(ws + 4227072);        //    16,384 B
  float* pos4  = (float*)(ws + 4243456);        //    16,384 B
  float* spart = (float*)(ws + 4259840);        // 1,048,576 B (32 x 8192)
  float* gpart = (float*)(ws + 5308416);        //     8,192 B (2048)
  float* cpart = (float*)(ws + 5316608);        //       128 B (32)
  float* out = (float*)d_out;

  prep_all<<<dim3(656), dim3(256), 0, stream>>>(h_i, h_j, ax, sx, hbf, axG, nall, nsub, pos4);
  main_fused<<<dim3(1536), dim3(256), 0, stream>>>(G, sx, axG, nall, nsub, hbf, spart, gpart);
  epilogue1<<<dim3(32), dim3(256), 0, stream>>>(spart, pos4, cpart);
  final_sum<<<dim3(1), dim3(256), 0, stream>>>(cpart, gpart, out);
}

// Round 11
// 58.558 us; speedup vs baseline: 1.1361x; 1.1361x over previous
//
#include <hip/hip_runtime.h>
#include <hip/hip_bf16.h>

typedef __attribute__((ext_vector_type(4)))  float f32x4;
typedef __attribute__((ext_vector_type(16))) float f32x16;
typedef __attribute__((ext_vector_type(8)))  short s16x8;
typedef unsigned short u16;
typedef unsigned int u32;

#define ALPHA 1.6986436f          /* sqrt(2*log2(e)) : dot(a*h, a*h) = sim*log2e */
#define LN2F  0.69314718056f
#define COFF  128.0f              /* static log2-domain offset for softmax */

__device__ __forceinline__ u16 f2bf(float x) {
  union { float f; u32 u; } v; v.f = x;
  u32 r = v.u + 0x7fffu + ((v.u >> 16) & 1u);
  return (u16)(r >> 16);
}

#if __has_builtin(__builtin_amdgcn_exp2f)
__device__ __forceinline__ float fexp2(float x) { return __builtin_amdgcn_exp2f(x); }
#else
__device__ __forceinline__ float fexp2(float x) { return exp2f(x); }
#endif
#if __has_builtin(__builtin_amdgcn_logf)
__device__ __forceinline__ float flog2(float x) { return __builtin_amdgcn_logf(x); }
#else
__device__ __forceinline__ float flog2(float x) { return log2f(x); }
#endif

// 8x fp32 -> packed bf16 (RNE) in 4 instructions
__device__ __forceinline__ s16x8 cvt8(float4 a, float4 b) {
  union { u32 w[4]; s16x8 v; } u;
  asm("v_cvt_pk_bf16_f32 %0, %1, %2" : "=v"(u.w[0]) : "v"(a.x), "v"(a.y));
  asm("v_cvt_pk_bf16_f32 %0, %1, %2" : "=v"(u.w[1]) : "v"(a.z), "v"(a.w));
  asm("v_cvt_pk_bf16_f32 %0, %1, %2" : "=v"(u.w[2]) : "v"(b.x), "v"(b.y));
  asm("v_cvt_pk_bf16_f32 %0, %1, %2" : "=v"(u.w[3]) : "v"(b.z), "v"(b.w));
  return u.v;
}

__device__ __forceinline__ f32x16 mfma32(s16x8 a, s16x8 b, f32x16 c) {
  return __builtin_amdgcn_mfma_f32_32x32x16_bf16(a, b, c, 0, 0, 0);
}
__device__ __forceinline__ f32x16 zero16() {
  f32x16 z;
#pragma unroll
  for (int i = 0; i < 16; ++i) z[i] = 0.f;
  return z;
}
__device__ __forceinline__ void gl16(const void* g, void* l) {
  __builtin_amdgcn_global_load_lds(
      (const __attribute__((address_space(1))) u32*)g,
      (__attribute__((address_space(3))) u32*)l, 16, 0, 0);
}

// =================== prep (fused): hbf + pos4 | axG + nall | nsub ============
// hbf row r: byte off = r*256 + ((2k) ^ ((r&7)<<4)), bf16 scaled by ALPHA.
// axG[kc][d][32B]: bf16(all_x[kc*16+kk][d]) at byte kc*4096 + d*32 + kk*2.
__global__ __launch_bounds__(256)
void prep_all(const float* __restrict__ h_i, const float* __restrict__ h_j,
              const float* __restrict__ all_x, const float* __restrict__ subx,
              u16* __restrict__ hbf, u16* __restrict__ axG,
              float* __restrict__ nall, float* __restrict__ nsub,
              float* __restrict__ pos4) {
  __shared__ float tile[64 * 132];
  int bid = blockIdx.x, tid = threadIdx.x;
  if (bid < 512) {
    // ---- hbf + pos4 ----
    int t = bid * 256 + tid;
    int row = t >> 4, kb = t & 15;
    const float* src = (row < 4096 ? h_i + (size_t)row * 128
                                   : h_j + (size_t)(row - 4096) * 128) + kb * 8;
    float4 f0 = *(const float4*)(src);
    float4 f1 = *(const float4*)(src + 4);
    float4 sa = {ALPHA * f0.x, ALPHA * f0.y, ALPHA * f0.z, ALPHA * f0.w};
    float4 sb = {ALPHA * f1.x, ALPHA * f1.y, ALPHA * f1.z, ALPHA * f1.w};
    s16x8 o = cvt8(sa, sb);
    char* dst = (char*)hbf + (size_t)row * 256 + ((kb * 16) ^ ((row & 7) << 4));
    *(s16x8*)dst = o;
    if (row < 4096) {   // fp32-exact positives
      const float* srcj = h_j + (size_t)row * 128 + kb * 8;
      float4 g0 = *(const float4*)(srcj);
      float4 g1 = *(const float4*)(srcj + 4);
      float dp = f0.x * g0.x + f0.y * g0.y + f0.z * g0.z + f0.w * g0.w
               + f1.x * g1.x + f1.y * g1.y + f1.z * g1.z + f1.w * g1.w;
      dp += __shfl_xor(dp, 1, 64);
      dp += __shfl_xor(dp, 2, 64);
      dp += __shfl_xor(dp, 4, 64);
      dp += __shfl_xor(dp, 8, 64);
      if ((tid & 15) == 0) pos4[row] = 2.0f * dp;
    }
  } else if (bid < 640) {
    // ---- axG + nall (64 k rows of all_x per block) ----
    int ab = bid - 512;           // 0..127
    int k0 = ab * 64;
#pragma unroll
    for (int j = 0; j < 8; ++j) {
      int idx = (j * 256 + tid) * 4;
      int kk = idx >> 7, d = idx & 127;
      *(float4*)&tile[kk * 132 + d] = *(const float4*)&all_x[(size_t)(k0 + kk) * 128 + d];
    }
    __syncthreads();
    {
      int kk = tid >> 2, q = tid & 3;
      float s = 0.f;
#pragma unroll
      for (int dd = 0; dd < 32; ++dd) { float v = tile[kk * 132 + q * 32 + dd]; s += v * v; }
      s += __shfl_xor(s, 1, 64);
      s += __shfl_xor(s, 2, 64);
      if (q == 0) nall[k0 + kk] = s;
    }
#pragma unroll
    for (int half = 0; half < 2; ++half) {
      int tgt = half * 256 + tid;
      int f = tgt >> 7, d = tgt & 127;    // kc-local f in 0..3
      int kc = ab * 4 + f;
      u16* dp = axG + (size_t)kc * 2048 + d * 16;
      s16x8 o0, o1;
#pragma unroll
      for (int kk = 0; kk < 8; ++kk) {
        o0[kk] = (short)f2bf(tile[(f * 16 + kk) * 132 + d]);
        o1[kk] = (short)f2bf(tile[(f * 16 + 8 + kk) * 132 + d]);
      }
      ((s16x8*)dp)[0] = o0; ((s16x8*)dp)[1] = o1;
    }
  } else {
    // ---- nsub ----
    int i = (bid - 640) * 256 + tid;
    const float* p = subx + (size_t)i * 128;
    float s = 0.f;
#pragma unroll
    for (int c = 0; c < 32; ++c) {
      float4 v = ((const float4*)p)[c];
      s += v.x * v.x + v.y * v.y + v.z * v.z + v.w * v.w;
    }
    nsub[i] = s;
  }
}

// =================== main (fused): graph | contrast ==========================
// even bid -> graph (gid = bid>>1, 1024): mt = gid>>3 (32 rows), kq = gid&7
//   (1024 k, 16 steps of 64). Depth-3 G pipeline + A-PREFETCH ONE STEP AHEAD,
//   A-loads ordered BEFORE the G issue: the MFMA's in-order vmcnt wait on A(s)
//   then drains only L_{s+1} (needed by this step's commit) and leaves
//   L_{s+2}, L_{s+3}, A(s+1) in flight across the raw (lgkm-only) barrier.
// odd bid -> contrast (cid = bid>>1, 1024): rt = cid>>5 (256 rows), oct =
//   cid&31 (256 cols, 8 steps of 32); diag masks behind wave-uniform branch.
__global__ __launch_bounds__(256, 3)
void main_fused(const float* __restrict__ G, const float* __restrict__ subx,
                const u16* __restrict__ axG, const float* __restrict__ nall,
                const float* __restrict__ nsub, const u16* __restrict__ hbf,
                float* __restrict__ spart, float* __restrict__ gpart) {
  __shared__ char pool[16640];
  int bid = blockIdx.x, tid = threadIdx.x;
  int lane = tid & 63, w = tid >> 6, il = lane & 31, hi = lane >> 5;

  if ((bid & 1) == 0) {
    // ------------------ graph ------------------
    int gid = bid >> 1;
    int mt = gid >> 3, kq = gid & 7;
    int i0 = mt * 32;
    int kbase = kq * 1024;
    int srow = tid >> 3, s8 = tid & 7;
    u16 (*gtile)[32][64] = (u16(*)[32][64])pool;          // 8 KB
    float* nll  = (float*)(pool + 8192);                  // 4 KB
    float* wsum = (float*)(pool + 12288);
    const float* gsrc = G + (size_t)(i0 + srow) * 8192 + kbase + s8 * 4;
    int sw_w = (srow & 7) << 4;
    int wo0 = ((s8 << 3))      ^ sw_w;
    int wo1 = (64 | (s8 << 3)) ^ sw_w;
    char* wb0 = (char*)&gtile[0][srow][0];
    char* wb1 = (char*)&gtile[1][srow][0];
    int swr = (il & 7) << 4;
    const char* aBase = (const char*)axG + (size_t)(kq * 64) * 4096
                      + (size_t)w * 1024 + il * 32 + hi * 16;

    // preload nall slice (4 KB) into LDS; syncthreads drains before pipeline
    *(float4*)&nll[tid * 4] = *(const float4*)&nall[kbase + tid * 4];
    __syncthreads();

    f32x16 acc = zero16();
    float rsum = 0.f, nsum = 0.f;
    float4 g0A, g0B, g1A, g1B, g2A, g2B;   // depth-3 slots: slot k%3 <- L_k
    s16x8 aU0, aU1, aU2, aU3, aV0, aV1, aV2, aV3;  // A cur/next double-buffer

#define GISSUE(S, GA, GB)                                              \
    { const float* p_ = gsrc + (S) * 64;                               \
      GA = *(const float4*)p_; GB = *(const float4*)(p_ + 32); }

#define APRE(S, A0_, A1_, A2_, A3_)                                    \
    { const char* aB_ = aBase + (size_t)((S) * 4) * 4096;              \
      A0_ = *(const s16x8*)(aB_);                                      \
      A1_ = *(const s16x8*)(aB_ + 4096);                               \
      A2_ = *(const s16x8*)(aB_ + 8192);                               \
      A3_ = *(const s16x8*)(aB_ + 12288); }

#define GCOMMIT(GA, GB, DSTB, SC)                                                  \
    { u32 c0_, c1_, c2_, c3_;                                                      \
      asm("v_cvt_pk_bf16_f32 %0, %1, %2" : "=v"(c0_) : "v"(GA.x), "v"(GA.y));      \
      asm("v_cvt_pk_bf16_f32 %0, %1, %2" : "=v"(c1_) : "v"(GA.z), "v"(GA.w));      \
      asm("v_cvt_pk_bf16_f32 %0, %1, %2" : "=v"(c2_) : "v"(GB.x), "v"(GB.y));      \
      asm("v_cvt_pk_bf16_f32 %0, %1, %2" : "=v"(c3_) : "v"(GB.z), "v"(GB.w));      \
      *(uint2*)((DSTB) + wo0) = make_uint2(c0_, c1_);                              \
      *(uint2*)((DSTB) + wo1) = make_uint2(c2_, c3_);                              \
      float4 NA = *(const float4*)&nll[(SC) * 64 + s8 * 4];                        \
      float4 NB = *(const float4*)&nll[(SC) * 64 + s8 * 4 + 32];                   \
      rsum += GA.x + GA.y + GA.z + GA.w + GB.x + GB.y + GB.z + GB.w;               \
      nsum += GA.x * NA.x + GA.y * NA.y + GA.z * NA.z + GA.w * NA.w                \
            + GB.x * NB.x + GB.y * NB.y + GB.z * NB.z + GB.w * NB.w; }

#define GBAR()                                                \
    asm volatile("s_waitcnt lgkmcnt(0)" ::: "memory");        \
    __builtin_amdgcn_sched_barrier(0);                        \
    __builtin_amdgcn_s_barrier();                             \
    __builtin_amdgcn_sched_barrier(0);

#define GSTEP(S, IA, IB, CA, CB, U0, U1, U2, U3, V0, V1, V2, V3)                   \
    { if ((S) < 15) APRE((S) + 1, V0, V1, V2, V3);                                 \
      __builtin_amdgcn_sched_barrier(0);                                           \
      if ((S) <= 12) GISSUE((S) + 3, IA, IB);                                      \
      __builtin_amdgcn_sched_barrier(0);                                           \
      const char* rb_ = (const char*)&gtile[(S) & 1][il][0];                       \
      s16x8 B0 = *(const s16x8*)(rb_ + ((0  + hi * 16) ^ swr));                    \
      s16x8 B1 = *(const s16x8*)(rb_ + ((32 + hi * 16) ^ swr));                    \
      s16x8 B2 = *(const s16x8*)(rb_ + ((64 + hi * 16) ^ swr));                    \
      s16x8 B3 = *(const s16x8*)(rb_ + ((96 + hi * 16) ^ swr));                    \
      acc = mfma32(U0, B0, acc);                                                   \
      acc = mfma32(U1, B1, acc);                                                   \
      acc = mfma32(U2, B2, acc);                                                   \
      acc = mfma32(U3, B3, acc);                                                   \
      if ((S) <= 14) GCOMMIT(CA, CB, ((((S) + 1) & 1) ? wb1 : wb0), (S) + 1);      \
      GBAR(); }

    // prologue: L0 issued, A(0) prefetched (older than L1/L2!), L1/L2 flying.
    // Commit L0 waits only up to L0 -> A(0), L1, L2 stay outstanding.
    GISSUE(0, g0A, g0B);
    APRE(0, aU0, aU1, aU2, aU3);
    GISSUE(1, g1A, g1B);
    GISSUE(2, g2A, g2B);
    GCOMMIT(g0A, g0B, wb0, 0);
    GBAR();

#define GSIX(B)                                                                \
    GSTEP((B) + 0, g0A, g0B, g1A, g1B, aU0, aU1, aU2, aU3, aV0, aV1, aV2, aV3) \
    GSTEP((B) + 1, g1A, g1B, g2A, g2B, aV0, aV1, aV2, aV3, aU0, aU1, aU2, aU3) \
    GSTEP((B) + 2, g2A, g2B, g0A, g0B, aU0, aU1, aU2, aU3, aV0, aV1, aV2, aV3) \
    GSTEP((B) + 3, g0A, g0B, g1A, g1B, aV0, aV1, aV2, aV3, aU0, aU1, aU2, aU3) \
    GSTEP((B) + 4, g1A, g1B, g2A, g2B, aU0, aU1, aU2, aU3, aV0, aV1, aV2, aV3) \
    GSTEP((B) + 5, g2A, g2B, g0A, g0B, aV0, aV1, aV2, aV3, aU0, aU1, aU2, aU3)

    GSIX(0)
    GSIX(6)
    GSTEP(12, g0A, g0B, g1A, g1B, aU0, aU1, aU2, aU3, aV0, aV1, aV2, aV3)
    GSTEP(13, g1A, g1B, g2A, g2B, aV0, aV1, aV2, aV3, aU0, aU1, aU2, aU3)
    GSTEP(14, g2A, g2B, g0A, g0B, aU0, aU1, aU2, aU3, aV0, aV1, aV2, aV3)
    GSTEP(15, g0A, g0B, g1A, g1B, aV0, aV1, aV2, aV3, aU0, aU1, aU2, aU3)
#undef GSIX
#undef GSTEP
#undef GBAR
#undef GCOMMIT
#undef APRE
#undef GISSUE

    // epilogue: acc[r] = y[i][d], d = w*32 + (r&3)+8*(r>>2)+4*hi ; + rsum/nsum
    float p = rsum * nsub[i0 + srow] + nsum;
    const float* sxr = subx + (size_t)(i0 + il) * 128 + w * 32 + hi * 4;
#pragma unroll
    for (int rq = 0; rq < 4; ++rq) {
      float4 sx = *(const float4*)(sxr + rq * 8);
      p -= 2.0f * (acc[rq * 4 + 0] * sx.x + acc[rq * 4 + 1] * sx.y +
                   acc[rq * 4 + 2] * sx.z + acc[rq * 4 + 3] * sx.w);
    }
#pragma unroll
    for (int d = 1; d < 64; d <<= 1) p += __shfl_xor(p, d, 64);
    if (lane == 0) wsum[w] = p;
    __syncthreads();
    if (tid == 0) gpart[gid] = wsum[0] + wsum[1] + wsum[2] + wsum[3];
  } else {
    // ------------------ contrast ------------------
    int cid = bid >> 1;
    int rt = cid >> 5, oct = cid & 31;
    int C0 = oct * 256;
    int rowbase = rt * 256 + w * 64;
    char (*clds)[8192] = (char(*)[8192])pool;
    s16x8 bf0[8], bf1[8];
#pragma unroll
    for (int rs = 0; rs < 2; ++rs) {
      int r = rowbase + rs * 32 + il;
      const char* rp = (const char*)hbf + (size_t)r * 256;
      int sw = (r & 7) << 4;
#pragma unroll
      for (int ks = 0; ks < 8; ++ks) {
        s16x8 v = *(const s16x8*)(rp + ((ks * 32 + hi * 16) ^ sw));
        if (rs == 0) bf0[ks] = v; else bf1[ks] = v;
      }
    }
    float s0 = 0.f, s1 = 0.f;
    auto stage = [&](int buf, int t) {
      const char* src = (const char*)hbf + (size_t)(C0 + t * 32) * 256 + tid * 16;
      char* dst = &clds[buf][0] + tid * 16;
      gl16(src, dst);
      gl16(src + 4096, dst + 4096);
    };
    stage(0, 0);
    __syncthreads();
    int cur = 0;
    for (int t = 0; t < 8; ++t) {
      if (t < 7) stage(cur ^ 1, t + 1);
      const char* basep = &clds[cur][0];
      s16x8 af[8];
#pragma unroll
      for (int ks = 0; ks < 8; ++ks)
        af[ks] = *(const s16x8*)(basep + il * 256 + ((ks * 32 + hi * 16) ^ ((il & 7) << 4)));
      f32x16 A0 = zero16(), A1 = zero16();
#pragma unroll
      for (int ks = 0; ks < 8; ++ks) {
        A0 = mfma32(af[ks], bf0[ks], A0);
        A1 = mfma32(af[ks], bf1[ks], A1);
      }
      int cb = C0 + t * 32;
      bool d0 = (cb == rowbase), d1 = (cb == rowbase + 32);
      if (!(d0 | d1)) {      // wave-uniform fast path: no diagonal in this tile
#pragma unroll
        for (int r = 0; r < 16; ++r) {
          s0 += fexp2(A0[r] - COFF);
          s1 += fexp2(A1[r] - COFF);
        }
      } else {
#pragma unroll
        for (int r = 0; r < 16; ++r) {
          int jc = (r & 3) + 8 * (r >> 2) + 4 * hi;
          float t0 = fexp2(A0[r] - COFF);
          float t1 = fexp2(A1[r] - COFF);
          if (d0 && jc == il) t0 = 0.f;
          if (d1 && jc == il) t1 = 0.f;
          s0 += t0; s1 += t1;
        }
      }
      __syncthreads();
      cur ^= 1;
    }
    s0 += __shfl_xor(s0, 32, 64);
    s1 += __shfl_xor(s1, 32, 64);
    if (hi == 0) {
      spart[oct * 8192 + rowbase + il]      = s0;
      spart[oct * 8192 + rowbase + 32 + il] = s1;
    }
  }
}

// =================== epilogue stage 1: per-row lse, 32-block parallel ========
__global__ __launch_bounds__(256)
void epilogue1(const float* __restrict__ spart, const float* __restrict__ pos4,
               float* __restrict__ cpart) {
  int tid = threadIdx.x;
  int row = blockIdx.x * 256 + tid;
  float S = 0.f;
#pragma unroll
  for (int o = 0; o < 32; ++o) S += spart[o * 8192 + row];
  float c = LN2F * (COFF + flog2(S)) - pos4[row & 4095];
#pragma unroll
  for (int d = 1; d < 64; d <<= 1) c += __shfl_xor(c, d, 64);
  __shared__ float ws4[4];
  int l = tid & 63, w = tid >> 6;
  if (l == 0) ws4[w] = c;
  __syncthreads();
  if (tid == 0) cpart[blockIdx.x] = ws4[0] + ws4[1] + ws4[2] + ws4[3];
}

// =================== final deterministic scalar reduction ====================
__global__ __launch_bounds__(256)
void final_sum(const float* __restrict__ cpart, const float* __restrict__ gpart,
               float* __restrict__ out) {
  int tid = threadIdx.x;
  double gd = 0.0;
  for (int idx = tid; idx < 1024; idx += 256) gd += (double)gpart[idx];
  double cd = (tid < 32) ? (double)cpart[tid] : 0.0;
#pragma unroll
  for (int d = 1; d < 64; d <<= 1) {
    cd += __shfl_xor(cd, d, 64);
    gd += __shfl_xor(gd, d, 64);
  }
  __shared__ double wc[4], wg[4];
  int l = tid & 63, w = tid >> 6;
  if (l == 0) { wc[w] = cd; wg[w] = gd; }
  __syncthreads();
  if (tid == 0) {
    double C = wc[0] + wc[1] + wc[2] + wc[3];
    double Gs = wg[0] + wg[1] + wg[2] + wg[3];
    out[0] = (float)(C / 8192.0 + Gs / (4096.0 * 8192.0));
  }
}

extern "C" void kernel_launch(void* const* d_in, const int* in_sizes, int n_in,
                              void* d_out, int out_size, void* d_ws, size_t ws_size,
                              hipStream_t stream) {
  const float* h_i = (const float*)d_in[0];
  const float* h_j = (const float*)d_in[1];
  const float* G   = (const float*)d_in[2];
  const float* sx  = (const float*)d_in[3];
  const float* ax  = (const float*)d_in[4];
  char* ws = (char*)d_ws;
  u16*   hbf   = (u16*)(ws);                    // 2,097,152 B
  u16*   axG   = (u16*)(ws + 2097152);          // 2,097,152 B (512 kc x 4KB)
  float* nall  = (float*)(ws + 4194304);        //    32,768 B
  float* nsub  = (float*)(ws + 4227072);        //    16,384 B
  float* pos4  = (float*)(ws + 4243456);        //    16,384 B
  float* spart = (float*)(ws + 4259840);        // 1,048,576 B (32 x 8192)
  float* gpart = (float*)(ws + 5308416);        //     4,096 B (1024)
  float* cpart = (float*)(ws + 5312512);        //       128 B (32)
  float* out = (float*)d_out;

  prep_all<<<dim3(656), dim3(256), 0, stream>>>(h_i, h_j, ax, sx, hbf, axG, nall, nsub, pos4);
  main_fused<<<dim3(2048), dim3(256), 0, stream>>>(G, sx, axG, nall, nsub, hbf, spart, gpart);
  epilogue1<<<dim3(32), dim3(256), 0, stream>>>(spart, pos4, cpart);
  final_sum<<<dim3(1), dim3(256), 0, stream>>>(cpart, gpart, out);
}